// Round 1
// baseline (105.901 us; speedup 1.0000x reference)
//
#include <hip/hip_runtime.h>

#define NCH 26
#define CPB 256          // cells per block
#define THREADS 256

__device__ __forceinline__ float iou_pair(const float* __restrict__ b,
                                          const float* __restrict__ g) {
    const float inv_s = 1.0f / 7.0f;
    float x1 = b[0] * inv_s - b[2] * 0.5f;
    float y1 = b[1] * inv_s - b[3] * 0.5f;
    float x2 = b[0] * inv_s + b[2] * 0.5f;
    float y2 = b[1] * inv_s + b[3] * 0.5f;
    float u1 = g[0] * inv_s - g[2] * 0.5f;
    float v1 = g[1] * inv_s - g[3] * 0.5f;
    float u2 = g[0] * inv_s + g[2] * 0.5f;
    float v2 = g[1] * inv_s + g[3] * 0.5f;
    float a1 = (x2 - x1) * (y2 - y1);
    float a2 = (u2 - u1) * (v2 - v1);
    float left   = fmaxf(x1, u1);
    float right  = fminf(x2, u2);
    float top    = fmaxf(y1, v1);
    float bottom = fminf(y2, v2);
    bool valid = (left < right) && (top < bottom);
    float inter = valid ? (right - left) * (bottom - top) : 0.0f;
    float uni = a1 + a2 - inter;
    return valid ? inter / uni : 0.0f;
}

__global__ __launch_bounds__(THREADS) void yolo_loss_main(
        const float* __restrict__ predict,
        const float* __restrict__ label,
        float* __restrict__ partials,
        int n_cells) {
    __shared__ float sp[CPB * NCH];
    __shared__ float sl[CPB * NCH];

    const int tid = threadIdx.x;
    const int bid = blockIdx.x;
    const long long base = (long long)bid * CPB * NCH;   // float index
    const long long total = (long long)n_cells * NCH;

    // Coalesced float4 staging: 256*26 = 6656 floats = 1664 float4 per array.
    const int n4 = CPB * NCH / 4;  // 1664
    const float4* p4 = (const float4*)(predict + base);
    const float4* l4 = (const float4*)(label + base);
    float4* sp4 = (float4*)sp;
    float4* sl4 = (float4*)sl;
    if (base + CPB * NCH <= total) {
        for (int i = tid; i < n4; i += THREADS) {
            sp4[i] = p4[i];
            sl4[i] = l4[i];
        }
    } else {
        // tail block: scalar guarded loads
        for (int i = tid; i < CPB * NCH; i += THREADS) {
            long long g = base + i;
            sp[i] = (g < total) ? predict[g] : 0.0f;
            sl[i] = (g < total) ? label[g] : 0.0f;
        }
    }
    __syncthreads();

    float partial = 0.0f;
    long long cell = (long long)bid * CPB + tid;
    if (cell < n_cells) {
        const float* p = &sp[tid * NCH];
        const float* l = &sl[tid * NCH];

        float conf_lab = l[4];
        float coord_m = (conf_lab > 0.0f) ? 1.0f : 0.0f;
        float noobj_m = (conf_lab == 0.0f) ? 1.0f : 0.0f;

        // noobj base term
        float acc_noobj = noobj_m * (p[4] * p[4] + p[9] * p[9]);

        // class loss
        float class_s = 0.0f;
        #pragma unroll
        for (int k = 10; k < 26; ++k) {
            float d = p[k] - l[k];
            class_s += d * d;
        }

        float iou1 = iou_pair(p + 0, l);
        float iou2 = iou_pair(p + 5, l);
        bool pick1 = iou1 > iou2;

        const float* sel = pick1 ? (p + 0) : (p + 5);
        float dx = sel[0] - l[0];
        float dy = sel[1] - l[1];
        float dw = sqrtf(sel[2]) - sqrtf(l[2]);
        float dh = sqrtf(sel[3]) - sqrtf(l[3]);
        float coord_cell = dx * dx + dy * dy + dw * dw + dh * dh;

        float csel  = pick1 ? p[4] : p[9];
        float iousel = pick1 ? iou1 : iou2;
        float t = csel - iousel;
        float obj_c = t * t;

        float cother = pick1 ? p[9] : p[4];
        acc_noobj += coord_m * cother * cother;

        partial = 5.0f * coord_m * coord_cell
                + coord_m * obj_c
                + 0.5f * acc_noobj
                + coord_m * class_s;
    }

    // block reduction: wave64 shuffle, then cross-wave LDS
    #pragma unroll
    for (int off = 32; off > 0; off >>= 1)
        partial += __shfl_down(partial, off, 64);

    __shared__ float wsum[THREADS / 64];
    if ((tid & 63) == 0) wsum[tid >> 6] = partial;
    __syncthreads();
    if (tid == 0) {
        float s = 0.0f;
        #pragma unroll
        for (int w = 0; w < THREADS / 64; ++w) s += wsum[w];
        partials[bid] = s;
    }
}

__global__ __launch_bounds__(256) void yolo_loss_finalize(
        const float* __restrict__ partials, int n, float inv_n,
        float* __restrict__ out) {
    float s = 0.0f;
    for (int i = threadIdx.x; i < n; i += 256) s += partials[i];
    #pragma unroll
    for (int off = 32; off > 0; off >>= 1)
        s += __shfl_down(s, off, 64);
    __shared__ float wsum[4];
    if ((threadIdx.x & 63) == 0) wsum[threadIdx.x >> 6] = s;
    __syncthreads();
    if (threadIdx.x == 0)
        out[0] = (wsum[0] + wsum[1] + wsum[2] + wsum[3]) * inv_n;
}

extern "C" void kernel_launch(void* const* d_in, const int* in_sizes, int n_in,
                              void* d_out, int out_size, void* d_ws, size_t ws_size,
                              hipStream_t stream) {
    const float* predict = (const float*)d_in[0];
    const float* label   = (const float*)d_in[1];
    float* out = (float*)d_out;
    float* partials = (float*)d_ws;

    int total  = in_sizes[0];          // B*7*7*26
    int n_cells = total / NCH;         // B*49
    int N = n_cells / 49;              // batch size
    int nblocks = (n_cells + CPB - 1) / CPB;

    yolo_loss_main<<<nblocks, THREADS, 0, stream>>>(predict, label, partials, n_cells);
    yolo_loss_finalize<<<1, 256, 0, stream>>>(partials, nblocks, 1.0f / (float)N, out);
}

// Round 2
// 101.496 us; speedup vs baseline: 1.0434x; 1.0434x over previous
//
#include <hip/hip_runtime.h>

#define NCH 26
#define CPB 256          // cells per block
#define THREADS 256
#define TILE_FLOATS (CPB * NCH)        // 6656 floats per array
#define TILE_BYTES  (TILE_FLOATS * 4)  // 26624 B per array

typedef __attribute__((address_space(3))) unsigned int  lds_u32_t;
typedef const __attribute__((address_space(1))) unsigned int glb_u32_t;

__device__ __forceinline__ float iou_pair_r(const float* b, const float* g) {
    const float inv_s = 1.0f / 7.0f;
    float x1 = b[0] * inv_s - b[2] * 0.5f;
    float y1 = b[1] * inv_s - b[3] * 0.5f;
    float x2 = b[0] * inv_s + b[2] * 0.5f;
    float y2 = b[1] * inv_s + b[3] * 0.5f;
    float u1 = g[0] * inv_s - g[2] * 0.5f;
    float v1 = g[1] * inv_s - g[3] * 0.5f;
    float u2 = g[0] * inv_s + g[2] * 0.5f;
    float v2 = g[1] * inv_s + g[3] * 0.5f;
    float a1 = (x2 - x1) * (y2 - y1);
    float a2 = (u2 - u1) * (v2 - v1);
    float left   = fmaxf(x1, u1);
    float right  = fminf(x2, u2);
    float top    = fmaxf(y1, v1);
    float bottom = fminf(y2, v2);
    bool valid = (left < right) && (top < bottom);
    float inter = valid ? (right - left) * (bottom - top) : 0.0f;
    float uni = a1 + a2 - inter;
    return valid ? inter / uni : 0.0f;
}

__global__ __launch_bounds__(THREADS) void yolo_loss_main(
        const float* __restrict__ predict,
        const float* __restrict__ label,
        float* __restrict__ partials,
        int n_cells) {
    __shared__ float sp[TILE_FLOATS];
    __shared__ float sl[TILE_FLOATS];

    const int tid = threadIdx.x;
    const int bid = blockIdx.x;
    const int wave = tid >> 6;
    const int lane = tid & 63;
    const long long base = (long long)bid * TILE_FLOATS;   // float index
    const long long total = (long long)n_cells * NCH;

    if (base + TILE_FLOATS <= total) {
        // Direct global->LDS DMA, width 16. Layout is linear: chunk c covers
        // bytes [c*1024, c*1024+1024) in both global tile and LDS (lane*16B).
        const char* gp = (const char*)(predict + base);
        const char* gl = (const char*)(label + base);
        #pragma unroll
        for (int c = 0; c < 7; ++c) {
            int chunk = wave + 4 * c;          // 4 waves cover 26 chunks (+2 idle slots)
            if (chunk < 26) {
                int off = chunk * 1024 + lane * 16;
                __builtin_amdgcn_global_load_lds(
                    (glb_u32_t*)(gp + off),
                    (lds_u32_t*)((char*)sp + off), 16, 0, 0);
                __builtin_amdgcn_global_load_lds(
                    (glb_u32_t*)(gl + off),
                    (lds_u32_t*)((char*)sl + off), 16, 0, 0);
            }
        }
    } else {
        // tail block (not hit for B=8192): guarded scalar staging
        for (int i = tid; i < TILE_FLOATS; i += THREADS) {
            long long g = base + i;
            sp[i] = (g < total) ? predict[g] : 0.0f;
            sl[i] = (g < total) ? label[g] : 0.0f;
        }
    }
    __syncthreads();   // compiler emits s_waitcnt vmcnt(0) before s_barrier

    float partial = 0.0f;
    long long cell = (long long)bid * CPB + tid;
    if (cell < n_cells) {
        // vectorized LDS->reg: 13 x float2 per array (8B-aligned: 104B stride)
        float p[NCH], l[NCH];
        const float2* pv = (const float2*)&sp[tid * NCH];
        const float2* lv = (const float2*)&sl[tid * NCH];
        #pragma unroll
        for (int k = 0; k < 13; ++k) {
            float2 a = pv[k]; p[2 * k] = a.x; p[2 * k + 1] = a.y;
            float2 b = lv[k]; l[2 * k] = b.x; l[2 * k + 1] = b.y;
        }

        float conf_lab = l[4];
        float coord_m = (conf_lab > 0.0f) ? 1.0f : 0.0f;
        float noobj_m = (conf_lab == 0.0f) ? 1.0f : 0.0f;

        float acc_noobj = noobj_m * (p[4] * p[4] + p[9] * p[9]);

        float class_s = 0.0f;
        #pragma unroll
        for (int k = 10; k < 26; ++k) {
            float d = p[k] - l[k];
            class_s += d * d;
        }

        float iou1 = iou_pair_r(p + 0, l);
        float iou2 = iou_pair_r(p + 5, l);
        bool pick1 = iou1 > iou2;

        float s0 = pick1 ? p[0] : p[5];
        float s1 = pick1 ? p[1] : p[6];
        float s2 = pick1 ? p[2] : p[7];
        float s3 = pick1 ? p[3] : p[8];
        float dx = s0 - l[0];
        float dy = s1 - l[1];
        float dw = sqrtf(s2) - sqrtf(l[2]);
        float dh = sqrtf(s3) - sqrtf(l[3]);
        float coord_cell = dx * dx + dy * dy + dw * dw + dh * dh;

        float csel   = pick1 ? p[4] : p[9];
        float iousel = pick1 ? iou1 : iou2;
        float t = csel - iousel;
        float obj_c = t * t;

        float cother = pick1 ? p[9] : p[4];
        acc_noobj += coord_m * cother * cother;

        partial = 5.0f * coord_m * coord_cell
                + coord_m * obj_c
                + 0.5f * acc_noobj
                + coord_m * class_s;
    }

    #pragma unroll
    for (int off = 32; off > 0; off >>= 1)
        partial += __shfl_down(partial, off, 64);

    __shared__ float wsum[THREADS / 64];
    if ((tid & 63) == 0) wsum[tid >> 6] = partial;
    __syncthreads();
    if (tid == 0) {
        float s = 0.0f;
        #pragma unroll
        for (int w = 0; w < THREADS / 64; ++w) s += wsum[w];
        partials[bid] = s;
    }
}

__global__ __launch_bounds__(256) void yolo_loss_finalize(
        const float* __restrict__ partials, int n, float inv_n,
        float* __restrict__ out) {
    float s = 0.0f;
    for (int i = threadIdx.x; i < n; i += 256) s += partials[i];
    #pragma unroll
    for (int off = 32; off > 0; off >>= 1)
        s += __shfl_down(s, off, 64);
    __shared__ float wsum[4];
    if ((threadIdx.x & 63) == 0) wsum[threadIdx.x >> 6] = s;
    __syncthreads();
    if (threadIdx.x == 0)
        out[0] = (wsum[0] + wsum[1] + wsum[2] + wsum[3]) * inv_n;
}

extern "C" void kernel_launch(void* const* d_in, const int* in_sizes, int n_in,
                              void* d_out, int out_size, void* d_ws, size_t ws_size,
                              hipStream_t stream) {
    const float* predict = (const float*)d_in[0];
    const float* label   = (const float*)d_in[1];
    float* out = (float*)d_out;
    float* partials = (float*)d_ws;

    int total   = in_sizes[0];         // B*7*7*26
    int n_cells = total / NCH;         // B*49
    int N = n_cells / 49;              // batch size
    int nblocks = (n_cells + CPB - 1) / CPB;

    yolo_loss_main<<<nblocks, THREADS, 0, stream>>>(predict, label, partials, n_cells);
    yolo_loss_finalize<<<1, 256, 0, stream>>>(partials, nblocks, 1.0f / (float)N, out);
}